// Round 7
// baseline (118.236 us; speedup 1.0000x reference)
//
#include <hip/hip_runtime.h>
#include <hip/hip_bf16.h>
#include <math.h>

#define KK 5
#define Bc 5.0f
#define NN 32768
#define DD 64
#define LL 63
#define PP 14
#define MIN_Wc 0.001f
#define MIN_Hc 0.001f
#define MIN_Dc 0.001f

typedef float f4 __attribute__((ext_vector_type(4)));
typedef float f32x4 __attribute__((ext_vector_type(4)));
typedef float f2 __attribute__((ext_vector_type(2)));
typedef short short8 __attribute__((ext_vector_type(8)));

__device__ __forceinline__ float rcp_fast(float v)  { return __builtin_amdgcn_rcpf(v); }
__device__ __forceinline__ float exp_fast(float v)  { return __expf(v); }
__device__ __forceinline__ float log_fast(float v)  { return __logf(v); }
__device__ __forceinline__ float tanh_fast(float v) {
    float e = exp_fast(2.0f * v);                 // overflow->inf->rcp->0->1: correct
    return 1.0f - 2.0f * rcp_fast(e + 1.0f);
}
__device__ __forceinline__ float softplus_fast(float v) {
    return (v > 15.0f) ? v : log_fast(1.0f + exp_fast(v));
}
__device__ __forceinline__ ushort to_bf16u(float v) {
    __hip_bfloat16 b = __float2bfloat16(v);
    return *(ushort*)&b;
}
__device__ __forceinline__ f2 splat2(float v) { f2 r; r.x = v; r.y = v; return r; }

// ---------------- kernel 0: pack W1 fp32 -> bf16 B[512][64] (n-major) -------
__global__ __launch_bounds__(256) void pack_b1(const float* __restrict__ W1,
                                               ushort* __restrict__ Bp) {
    int id = blockIdx.x * 256 + threadIdx.x;     // 0..32767
    int n = id >> 6, k = id & 63;
    float v = 0.f;
    if (n < 504 && k < 63) {
        int l = n >> 3, h = n & 7;
        v = W1[(l * 63 + k) * 8 + h];
    }
    Bp[id] = to_bf16u(v);
}

__device__ __forceinline__ short8 pack_a(f4 v0, f4 v1) {
    short8 a;
    a[0] = (short)to_bf16u(v0.x); a[1] = (short)to_bf16u(v0.y);
    a[2] = (short)to_bf16u(v0.z); a[3] = (short)to_bf16u(v0.w);
    a[4] = (short)to_bf16u(v1.x); a[5] = (short)to_bf16u(v1.y);
    a[6] = (short)to_bf16u(v1.z); a[7] = (short)to_bf16u(v1.w);
    return a;
}

// ---------------- fused kernel -----------------------------------------------
// grid (512, 4): x = 64-sample tile, y = 16-dim group (y==3 idx15 -> dim 0).
// causality: y<2 -> l<32 -> only k<32 contributes (W1 pre-masked) -> 1 MFMA.
#define H1S 136   // u16 row stride: 272B; 272/16=17 -> b128-aligned rows, 4-bank residue
__global__ __launch_bounds__(256, 8) void fused_kernel(
    const float* __restrict__ x, const float* __restrict__ init_param,
    const ushort* __restrict__ Bp, const float* __restrict__ b1,
    const float* __restrict__ W2, const float* __restrict__ b2,
    const float* __restrict__ W3, const float* __restrict__ b3,
    float* __restrict__ out)
{
    __shared__ ushort h1c[64 * H1S];   // [sample][128 outcols], bf16
    const int tid = threadIdx.x;
    const int s0 = blockIdx.x * 64;
    const int y  = blockIdx.y;
    const int lane = tid & 63;
    const int wave = __builtin_amdgcn_readfirstlane(tid >> 6);
    const int ln = lane & 15, qg = lane >> 4;
    const int m0 = wave * 16;

    // prefetch spline x values (per-lane gather, hidden behind phase 1)
    float xv[4];
    #pragma unroll
    for (int it = 0; it < 4; ++it) {
        int idx = wave * 4 + it;
        int dd = (y == 3 && idx == 15) ? 0 : y * 16 + 1 + idx;
        xv[it] = x[(size_t)(s0 + lane) * 64 + dd];
    }

    // A-fragments (fp32 -> bf16), verified layout: A[m=ln][k=qg*8+j]
    short8 a0, a1;
    {
        const float* xr = x + (size_t)(s0 + m0 + ln) * 64 + qg * 8;
        a0 = pack_a(*(const f4*)xr, *(const f4*)(xr + 4));
        a1 = (y >= 2) ? pack_a(*(const f4*)(xr + 32), *(const f4*)(xr + 36)) : a0;
    }

    // ---- phase 1: MFMA all 128 outcols for this wave's 16 samples ----
    #pragma unroll
    for (int nt = 0; nt < 8; ++nt) {
        int ncol = y * 128 + nt * 16 + ln;
        const short8* bp8 = (const short8*)(Bp + ncol * 64 + qg * 8);
        f32x4 acc = {0.f, 0.f, 0.f, 0.f};
        acc = __builtin_amdgcn_mfma_f32_16x16x32_bf16(a0, bp8[0], acc, 0, 0, 0);
        if (y >= 2)
            acc = __builtin_amdgcn_mfma_f32_16x16x32_bf16(a1, bp8[4], acc, 0, 0, 0);
        float bias = (ncol < 504) ? b1[ncol] : 0.f;
        #pragma unroll
        for (int r = 0; r < 4; ++r) {
            float v = tanh_fast(acc[r] + bias);
            h1c[(m0 + qg * 4 + r) * H1S + nt * 16 + ln] = to_bf16u(v);
        }
    }
    __syncthreads();   // the only barrier

    // hoisted h1 reads: this wave's 4 dims are 64 contiguous bytes per lane
    uint4 hv4[4];
    {
        const uint4* hp = (const uint4*)&h1c[lane * H1S + wave * 32];
        hv4[0] = hp[0]; hv4[1] = hp[1]; hv4[2] = hp[2]; hv4[3] = hp[3];
    }

    // ---- phase 2: layers 2,3 + spline, 4 dims per wave ----
    #pragma unroll 1
    for (int it = 0; it < 4; ++it) {
        int idx = wave * 4 + it;
        int dd = (y == 3 && idx == 15) ? 0 : y * 16 + 1 + idx;
        dd = __builtin_amdgcn_readfirstlane(dd);
        const float xf = xv[it];

        float p[PP];
        if (dd == 0) {
            #pragma unroll
            for (int i = 0; i < PP; ++i) p[i] = init_param[i];
        } else {
            const int l = dd - 1;
            uint4 hv = hv4[it];
            float h1f[8];
            h1f[0] = __uint_as_float(hv.x << 16);
            h1f[1] = __uint_as_float(hv.x & 0xFFFF0000u);
            h1f[2] = __uint_as_float(hv.y << 16);
            h1f[3] = __uint_as_float(hv.y & 0xFFFF0000u);
            h1f[4] = __uint_as_float(hv.z << 16);
            h1f[5] = __uint_as_float(hv.z & 0xFFFF0000u);
            h1f[6] = __uint_as_float(hv.w << 16);
            h1f[7] = __uint_as_float(hv.w & 0xFFFF0000u);

            // layer 2 (packed f2 -> v_pk_fma_f32)
            const f2* w2p = (const f2*)(W2 + l * 64);
            const f2* b2p = (const f2*)(b2 + l * 8);
            f2 h2p[4] = {b2p[0], b2p[1], b2p[2], b2p[3]};
            #pragma unroll
            for (int h = 0; h < 8; ++h) {
                f2 av = splat2(h1f[h]);
                #pragma unroll
                for (int j = 0; j < 4; ++j) h2p[j] += av * w2p[h * 4 + j];
            }
            float h2f[8];
            #pragma unroll
            for (int j = 0; j < 4; ++j) {
                h2f[2 * j]     = tanh_fast(h2p[j].x);
                h2f[2 * j + 1] = tanh_fast(h2p[j].y);
            }

            // layer 3 (packed)
            const f2* w3p = (const f2*)(W3 + l * 112);
            const f2* b3p = (const f2*)(b3 + l * PP);
            f2 pp[7];
            #pragma unroll
            for (int j = 0; j < 7; ++j) pp[j] = b3p[j];
            #pragma unroll
            for (int g = 0; g < 8; ++g) {
                f2 av = splat2(h2f[g]);
                #pragma unroll
                for (int j = 0; j < 7; ++j) pp[j] += av * w3p[g * 7 + j];
            }
            #pragma unroll
            for (int j = 0; j < 7; ++j) { p[2 * j] = pp[j].x; p[2 * j + 1] = pp[j].y; }
        }

        // ---- packed rational quadratic spline (w,h lanes in f2) ----
        // no max-subtraction: |p| small enough that exp can't overflow (R3-validated)
        f2 e[KK];
        #pragma unroll
        for (int i = 0; i < KK; ++i) { e[i].x = exp_fast(p[i]); e[i].y = exp_fast(p[KK + i]); }
        f2 es = e[0] + e[1] + e[2] + e[3] + e[4];
        f2 nrm; nrm.x = 0.995f * rcp_fast(es.x); nrm.y = 0.995f * rcp_fast(es.y);

        f2 cb[KK + 1];
        cb[0] = splat2(-Bc);
        f2 acc2 = splat2(0.f);
        const f2 minv = {MIN_Wc, MIN_Hc};
        #pragma unroll
        for (int i = 0; i < KK - 1; ++i) {
            acc2 += minv + nrm * e[i];
            cb[i + 1] = splat2(2.f * Bc) * acc2 - splat2(Bc);
        }
        cb[KK] = splat2(Bc);

        float d_[KK + 1];
        d_[0] = 1.0f; d_[KK] = 1.0f;
        #pragma unroll
        for (int i = 0; i < KK - 1; ++i) d_[i + 1] = MIN_Dc + softplus_fast(p[2 * KK + i]);

        const float xc = fminf(fmaxf(xf, -Bc), Bc);

        float icw = cb[0].x, ich = cb[0].y;
        float ibw = cb[1].x - cb[0].x, ih = cb[1].y - cb[0].y;
        float idv = d_[0], idvp1 = d_[1];
        #pragma unroll
        for (int i = 1; i < KK; ++i) {
            bool c = xc >= cb[i].x;
            f2 dif = cb[i + 1] - cb[i];
            icw   = c ? cb[i].x  : icw;
            ich   = c ? cb[i].y  : ich;
            ibw   = c ? dif.x    : ibw;
            ih    = c ? dif.y    : ih;
            idv   = c ? d_[i]    : idv;
            idvp1 = c ? d_[i + 1]: idvp1;
        }

        const float ibw_r = rcp_fast(ibw);
        const float idl = ih * ibw_r;
        const float theta = (xc - icw) * ibw_r;
        const float omt = 1.0f - theta;
        const float tmt = theta * omt;
        const float num = ih * (idl * theta * theta + idv * tmt);
        const float den = idl + (idv + idvp1 - 2.0f * idl) * tmt;
        const float dr = rcp_fast(den);
        const float outv = ich + num * dr;
        const float dnum = idl * idl * (idvp1 * theta * theta + 2.0f * idl * tmt + idv * omt * omt);
        const float ld = log_fast(dnum * dr * dr);   // log(dnum) - 2log(den)

        const bool inside = (xf >= -Bc) && (xf <= Bc);
        const float z = inside ? outv : xf;
        float ldv = inside ? ld : 0.0f;

        out[dd * NN + s0 + lane] = z;   // coalesced

        #pragma unroll
        for (int off = 32; off > 0; off >>= 1) ldv += __shfl_down(ldv, off);
        if (lane == 0) out[NN * DD + dd * (NN / 64) + blockIdx.x] = ldv;
    }
}

extern "C" void kernel_launch(void* const* d_in, const int* in_sizes, int n_in,
                              void* d_out, int out_size, void* d_ws, size_t ws_size,
                              hipStream_t stream) {
    const float* x          = (const float*)d_in[0];
    const float* init_param = (const float*)d_in[1];
    const float* W1         = (const float*)d_in[2];
    const float* b1         = (const float*)d_in[3];
    const float* W2         = (const float*)d_in[4];
    const float* b2         = (const float*)d_in[5];
    const float* W3         = (const float*)d_in[6];
    const float* b3         = (const float*)d_in[7];
    float* out = (float*)d_out;

    ushort* Bp = (ushort*)d_ws;            // 512*64 bf16 = 64 KB

    pack_b1<<<128, 256, 0, stream>>>(W1, Bp);
    fused_kernel<<<dim3(512, 4), 256, 0, stream>>>(x, init_param, Bp, b1,
                                                   W2, b2, W3, b3, out);
}

// Round 8
// 112.291 us; speedup vs baseline: 1.0529x; 1.0529x over previous
//
#include <hip/hip_runtime.h>
#include <hip/hip_bf16.h>
#include <math.h>

#define KK 5
#define Bc 5.0f
#define NN 32768
#define DD 64
#define LL 63
#define PP 14
#define MIN_Wc 0.001f
#define MIN_Hc 0.001f
#define MIN_Dc 0.001f

typedef float f4 __attribute__((ext_vector_type(4)));
typedef float f32x4 __attribute__((ext_vector_type(4)));
typedef float f2 __attribute__((ext_vector_type(2)));
typedef short short8 __attribute__((ext_vector_type(8)));

__device__ __forceinline__ float rcp_fast(float v)  { return __builtin_amdgcn_rcpf(v); }
__device__ __forceinline__ float exp_fast(float v)  { return __expf(v); }
__device__ __forceinline__ float log_fast(float v)  { return __logf(v); }
__device__ __forceinline__ float tanh_fast(float v) {
    float e = exp_fast(2.0f * v);                 // overflow->inf->rcp->0->1: correct
    return 1.0f - 2.0f * rcp_fast(e + 1.0f);
}
__device__ __forceinline__ float softplus_fast(float v) {
    return (v > 15.0f) ? v : log_fast(1.0f + exp_fast(v));
}
__device__ __forceinline__ ushort to_bf16u(float v) {
    __hip_bfloat16 b = __float2bfloat16(v);
    return *(ushort*)&b;
}
__device__ __forceinline__ f2 splat2(float v) { f2 r; r.x = v; r.y = v; return r; }

// ---------------- kernel 0: pack W1 fp32 -> bf16 B[512][64] (n-major) -------
__global__ __launch_bounds__(256) void pack_b1(const float* __restrict__ W1,
                                               ushort* __restrict__ Bp) {
    int id = blockIdx.x * 256 + threadIdx.x;     // 0..32767
    int n = id >> 6, k = id & 63;
    float v = 0.f;
    if (n < 504 && k < 63) {
        int l = n >> 3, h = n & 7;
        v = W1[(l * 63 + k) * 8 + h];
    }
    Bp[id] = to_bf16u(v);
}

__device__ __forceinline__ short8 pack_a(f4 v0, f4 v1) {
    short8 a;
    a[0] = (short)to_bf16u(v0.x); a[1] = (short)to_bf16u(v0.y);
    a[2] = (short)to_bf16u(v0.z); a[3] = (short)to_bf16u(v0.w);
    a[4] = (short)to_bf16u(v1.x); a[5] = (short)to_bf16u(v1.y);
    a[6] = (short)to_bf16u(v1.z); a[7] = (short)to_bf16u(v1.w);
    return a;
}

// ---- per-dim: layers 2,3 (packed f2) + RQS spline + stores -----------------
// dd wave-uniform; hv = 8 bf16 h1 values (ignored when dd==0). No arrays with
// dynamic indices anywhere -> everything stays in registers (R7 spill fix).
__device__ __forceinline__ void do_dim(
    int dd, float xf, uint4 hv, int s0, int lane, int bx,
    const float* __restrict__ init_param,
    const float* __restrict__ W2, const float* __restrict__ b2,
    const float* __restrict__ W3, const float* __restrict__ b3,
    float* __restrict__ out)
{
    float p[PP];
    if (dd == 0) {
        #pragma unroll
        for (int i = 0; i < PP; ++i) p[i] = init_param[i];
    } else {
        const int l = dd - 1;
        float h1f[8];
        h1f[0] = __uint_as_float(hv.x << 16);
        h1f[1] = __uint_as_float(hv.x & 0xFFFF0000u);
        h1f[2] = __uint_as_float(hv.y << 16);
        h1f[3] = __uint_as_float(hv.y & 0xFFFF0000u);
        h1f[4] = __uint_as_float(hv.z << 16);
        h1f[5] = __uint_as_float(hv.z & 0xFFFF0000u);
        h1f[6] = __uint_as_float(hv.w << 16);
        h1f[7] = __uint_as_float(hv.w & 0xFFFF0000u);

        // layer 2 (packed f2 -> v_pk_fma_f32)
        const f2* w2p = (const f2*)(W2 + l * 64);
        const f2* b2p = (const f2*)(b2 + l * 8);
        f2 h2p0 = b2p[0], h2p1 = b2p[1], h2p2 = b2p[2], h2p3 = b2p[3];
        #pragma unroll
        for (int h = 0; h < 8; ++h) {
            f2 av = splat2(h1f[h]);
            h2p0 += av * w2p[h * 4];
            h2p1 += av * w2p[h * 4 + 1];
            h2p2 += av * w2p[h * 4 + 2];
            h2p3 += av * w2p[h * 4 + 3];
        }
        float h2f[8];
        h2f[0] = tanh_fast(h2p0.x); h2f[1] = tanh_fast(h2p0.y);
        h2f[2] = tanh_fast(h2p1.x); h2f[3] = tanh_fast(h2p1.y);
        h2f[4] = tanh_fast(h2p2.x); h2f[5] = tanh_fast(h2p2.y);
        h2f[6] = tanh_fast(h2p3.x); h2f[7] = tanh_fast(h2p3.y);

        // layer 3 (packed)
        const f2* w3p = (const f2*)(W3 + l * 112);
        const f2* b3p = (const f2*)(b3 + l * PP);
        f2 pp0 = b3p[0], pp1 = b3p[1], pp2 = b3p[2], pp3 = b3p[3];
        f2 pp4 = b3p[4], pp5 = b3p[5], pp6 = b3p[6];
        #pragma unroll
        for (int g = 0; g < 8; ++g) {
            f2 av = splat2(h2f[g]);
            pp0 += av * w3p[g * 7];
            pp1 += av * w3p[g * 7 + 1];
            pp2 += av * w3p[g * 7 + 2];
            pp3 += av * w3p[g * 7 + 3];
            pp4 += av * w3p[g * 7 + 4];
            pp5 += av * w3p[g * 7 + 5];
            pp6 += av * w3p[g * 7 + 6];
        }
        p[0] = pp0.x; p[1] = pp0.y; p[2]  = pp1.x; p[3]  = pp1.y;
        p[4] = pp2.x; p[5] = pp2.y; p[6]  = pp3.x; p[7]  = pp3.y;
        p[8] = pp4.x; p[9] = pp4.y; p[10] = pp5.x; p[11] = pp5.y;
        p[12] = pp6.x; p[13] = pp6.y;
    }

    // ---- packed RQS spline (w=x-lane, h=y-lane of f2) ----
    // no max-subtraction (R3-validated: |p| small, exp safe)
    f2 e0, e1, e2, e3, e4;
    e0.x = exp_fast(p[0]); e0.y = exp_fast(p[KK]);
    e1.x = exp_fast(p[1]); e1.y = exp_fast(p[KK + 1]);
    e2.x = exp_fast(p[2]); e2.y = exp_fast(p[KK + 2]);
    e3.x = exp_fast(p[3]); e3.y = exp_fast(p[KK + 3]);
    e4.x = exp_fast(p[4]); e4.y = exp_fast(p[KK + 4]);
    f2 es = e0 + e1 + e2 + e3 + e4;
    f2 nrm; nrm.x = 0.995f * rcp_fast(es.x); nrm.y = 0.995f * rcp_fast(es.y);

    const f2 minv = {MIN_Wc, MIN_Hc};
    f2 cb0 = splat2(-Bc), acc2 = splat2(0.f);
    acc2 += minv + nrm * e0;  f2 cb1 = splat2(2.f * Bc) * acc2 - splat2(Bc);
    acc2 += minv + nrm * e1;  f2 cb2 = splat2(2.f * Bc) * acc2 - splat2(Bc);
    acc2 += minv + nrm * e2;  f2 cb3 = splat2(2.f * Bc) * acc2 - splat2(Bc);
    acc2 += minv + nrm * e3;  f2 cb4 = splat2(2.f * Bc) * acc2 - splat2(Bc);
    f2 cb5 = splat2(Bc);

    float d0 = 1.0f, d5 = 1.0f;
    float d1 = MIN_Dc + softplus_fast(p[10]);
    float d2 = MIN_Dc + softplus_fast(p[11]);
    float d3 = MIN_Dc + softplus_fast(p[12]);
    float d4 = MIN_Dc + softplus_fast(p[13]);

    const float xc = fminf(fmaxf(xf, -Bc), Bc);

    float icw = cb0.x, ich = cb0.y;
    float ibw = cb1.x - cb0.x, ih = cb1.y - cb0.y;
    float idv = d0, idvp1 = d1;
    {
        bool c = xc >= cb1.x; f2 dif = cb2 - cb1;
        icw = c ? cb1.x : icw; ich = c ? cb1.y : ich;
        ibw = c ? dif.x : ibw; ih  = c ? dif.y : ih;
        idv = c ? d1 : idv; idvp1 = c ? d2 : idvp1;
    }
    {
        bool c = xc >= cb2.x; f2 dif = cb3 - cb2;
        icw = c ? cb2.x : icw; ich = c ? cb2.y : ich;
        ibw = c ? dif.x : ibw; ih  = c ? dif.y : ih;
        idv = c ? d2 : idv; idvp1 = c ? d3 : idvp1;
    }
    {
        bool c = xc >= cb3.x; f2 dif = cb4 - cb3;
        icw = c ? cb3.x : icw; ich = c ? cb3.y : ich;
        ibw = c ? dif.x : ibw; ih  = c ? dif.y : ih;
        idv = c ? d3 : idv; idvp1 = c ? d4 : idvp1;
    }
    {
        bool c = xc >= cb4.x; f2 dif = cb5 - cb4;
        icw = c ? cb4.x : icw; ich = c ? cb4.y : ich;
        ibw = c ? dif.x : ibw; ih  = c ? dif.y : ih;
        idv = c ? d4 : idv; idvp1 = c ? d5 : idvp1;
    }

    const float ibw_r = rcp_fast(ibw);
    const float idl = ih * ibw_r;
    const float theta = (xc - icw) * ibw_r;
    const float omt = 1.0f - theta;
    const float tmt = theta * omt;
    const float num = ih * (idl * theta * theta + idv * tmt);
    const float den = idl + (idv + idvp1 - 2.0f * idl) * tmt;
    const float dr = rcp_fast(den);
    const float outv = ich + num * dr;
    const float dnum = idl * idl * (idvp1 * theta * theta + 2.0f * idl * tmt + idv * omt * omt);
    const float ld = log_fast(dnum * dr * dr);   // log(dnum) - 2log(den)

    const bool inside = (xf >= -Bc) && (xf <= Bc);
    const float z = inside ? outv : xf;
    float ldv = inside ? ld : 0.0f;

    out[dd * NN + s0 + lane] = z;   // coalesced

    #pragma unroll
    for (int off = 32; off > 0; off >>= 1) ldv += __shfl_down(ldv, off);
    if (lane == 0) out[NN * DD + dd * (NN / 64) + bx] = ldv;
}

// ---------------- fused kernel -----------------------------------------------
// grid (512, 4): x = 64-sample tile, y = 16-dim group (y==3 idx15 -> dim 0).
// causality: y<2 -> l<32 -> only k<32 contributes (W1 pre-masked) -> 1 MFMA.
#define H1S 136   // u16 row stride: 272B; rows 16B-aligned, 4-bank residue
__global__ __launch_bounds__(256, 8) void fused_kernel(
    const float* __restrict__ x, const float* __restrict__ init_param,
    const ushort* __restrict__ Bp, const float* __restrict__ b1,
    const float* __restrict__ W2, const float* __restrict__ b2,
    const float* __restrict__ W3, const float* __restrict__ b3,
    float* __restrict__ out)
{
    __shared__ ushort h1c[64 * H1S];   // [sample][128 outcols], bf16
    const int tid = threadIdx.x;
    const int s0 = blockIdx.x * 64;
    const int y  = blockIdx.y;
    const int bx = blockIdx.x;
    const int lane = tid & 63;
    const int wave = __builtin_amdgcn_readfirstlane(tid >> 6);
    const int ln = lane & 15, qg = lane >> 4;
    const int m0 = wave * 16;

    // spline x values (per-lane gather, hidden behind phase 1) — scalars, no array
    const float* xrow = x + (size_t)(s0 + lane) * 64;
    const int db = y * 16 + 1 + wave * 4;     // first dim of this wave's group
    float xv0 = xrow[db];
    float xv1 = xrow[db + 1];
    float xv2 = xrow[db + 2];
    float xv3 = xrow[(y == 3 && wave == 3) ? 0 : db + 3];

    // A-fragments (fp32 -> bf16), verified layout: A[m=ln][k=qg*8+j]
    short8 a0, a1;
    {
        const float* xr = x + (size_t)(s0 + m0 + ln) * 64 + qg * 8;
        a0 = pack_a(*(const f4*)xr, *(const f4*)(xr + 4));
        a1 = (y >= 2) ? pack_a(*(const f4*)(xr + 32), *(const f4*)(xr + 36)) : a0;
    }

    // ---- phase 1: MFMA all 128 outcols for this wave's 16 samples ----
    #pragma unroll
    for (int nt = 0; nt < 8; ++nt) {
        int ncol = y * 128 + nt * 16 + ln;
        const short8* bp8 = (const short8*)(Bp + ncol * 64 + qg * 8);
        f32x4 acc = {0.f, 0.f, 0.f, 0.f};
        acc = __builtin_amdgcn_mfma_f32_16x16x32_bf16(a0, bp8[0], acc, 0, 0, 0);
        if (y >= 2)
            acc = __builtin_amdgcn_mfma_f32_16x16x32_bf16(a1, bp8[4], acc, 0, 0, 0);
        float bias = (ncol < 504) ? b1[ncol] : 0.f;
        #pragma unroll
        for (int r = 0; r < 4; ++r) {
            float v = tanh_fast(acc[r] + bias);
            h1c[(m0 + qg * 4 + r) * H1S + nt * 16 + ln] = to_bf16u(v);
        }
    }
    __syncthreads();   // the only barrier

    // h1 fragments for this wave's 4 dims — 4 static b128 reads, scalars
    const uint4* hp = (const uint4*)&h1c[lane * H1S + wave * 32];
    uint4 hv0 = hp[0], hv1 = hp[1], hv2 = hp[2], hv3 = hp[3];

    // ---- phase 2: 4 dims, explicit calls (static everything) ----
    const int d0_ = db;
    do_dim(d0_,     xv0, hv0, s0, lane, bx, init_param, W2, b2, W3, b3, out);
    do_dim(d0_ + 1, xv1, hv1, s0, lane, bx, init_param, W2, b2, W3, b3, out);
    do_dim(d0_ + 2, xv2, hv2, s0, lane, bx, init_param, W2, b2, W3, b3, out);
    do_dim((y == 3 && wave == 3) ? 0 : d0_ + 3,
                    xv3, hv3, s0, lane, bx, init_param, W2, b2, W3, b3, out);
}

extern "C" void kernel_launch(void* const* d_in, const int* in_sizes, int n_in,
                              void* d_out, int out_size, void* d_ws, size_t ws_size,
                              hipStream_t stream) {
    const float* x          = (const float*)d_in[0];
    const float* init_param = (const float*)d_in[1];
    const float* W1         = (const float*)d_in[2];
    const float* b1         = (const float*)d_in[3];
    const float* W2         = (const float*)d_in[4];
    const float* b2         = (const float*)d_in[5];
    const float* W3         = (const float*)d_in[6];
    const float* b3         = (const float*)d_in[7];
    float* out = (float*)d_out;

    ushort* Bp = (ushort*)d_ws;            // 512*64 bf16 = 64 KB

    pack_b1<<<128, 256, 0, stream>>>(W1, Bp);
    fused_kernel<<<dim3(512, 4), 256, 0, stream>>>(x, init_param, Bp, b1,
                                                   W2, b2, W3, b3, out);
}

// Round 9
// 111.107 us; speedup vs baseline: 1.0642x; 1.0107x over previous
//
#include <hip/hip_runtime.h>
#include <hip/hip_bf16.h>
#include <math.h>

#define KK 5
#define Bc 5.0f
#define NN 32768
#define DD 64
#define LL 63
#define PP 14
#define MIN_Wc 0.001f
#define MIN_Hc 0.001f
#define MIN_Dc 0.001f

typedef float f4 __attribute__((ext_vector_type(4)));
typedef float f32x4 __attribute__((ext_vector_type(4)));
typedef float f2 __attribute__((ext_vector_type(2)));
typedef short short8 __attribute__((ext_vector_type(8)));

__device__ __forceinline__ float rcp_fast(float v)  { return __builtin_amdgcn_rcpf(v); }
__device__ __forceinline__ float exp_fast(float v)  { return __expf(v); }
__device__ __forceinline__ float log_fast(float v)  { return __logf(v); }
__device__ __forceinline__ float tanh_fast(float v) {
    float e = exp_fast(2.0f * v);                 // overflow->inf->rcp->0->1: correct
    return 1.0f - 2.0f * rcp_fast(e + 1.0f);
}
__device__ __forceinline__ float softplus_fast(float v) {
    return (v > 15.0f) ? v : log_fast(1.0f + exp_fast(v));
}
__device__ __forceinline__ ushort to_bf16u(float v) {
    __hip_bfloat16 b = __float2bfloat16(v);
    return *(ushort*)&b;
}
__device__ __forceinline__ f2 splat2(float v) { f2 r; r.x = v; r.y = v; return r; }
__device__ __forceinline__ f4 splat4(float v) { f4 r; r.x = v; r.y = v; r.z = v; r.w = v; return r; }

// ---------------- kernel 0: pack W1 fp32 -> bf16 B[512][64] (n-major) -------
__global__ __launch_bounds__(256) void pack_b1(const float* __restrict__ W1,
                                               ushort* __restrict__ Bp) {
    int id = blockIdx.x * 256 + threadIdx.x;     // 0..32767
    int n = id >> 6, k = id & 63;
    float v = 0.f;
    if (n < 504 && k < 63) {
        int l = n >> 3, h = n & 7;
        v = W1[(l * 63 + k) * 8 + h];
    }
    Bp[id] = to_bf16u(v);
}

__device__ __forceinline__ short8 pack_a(f4 v0, f4 v1) {
    short8 a;
    a[0] = (short)to_bf16u(v0.x); a[1] = (short)to_bf16u(v0.y);
    a[2] = (short)to_bf16u(v0.z); a[3] = (short)to_bf16u(v0.w);
    a[4] = (short)to_bf16u(v1.x); a[5] = (short)to_bf16u(v1.y);
    a[6] = (short)to_bf16u(v1.z); a[7] = (short)to_bf16u(v1.w);
    return a;
}

// per-dim LDS weight slot layout (floats, stride 216 = 864B, 16B-aligned):
// [0,64) W2[h][g]  [64,72) b2  [72,200) W3 padded [g][16] (14 used)  [200,216) b3 (14 used)
#define WSL 216

// ---- per-dim: layers 2,3 (LDS weights, f4 packed) + RQS spline + stores ----
__device__ __forceinline__ void do_dim(
    int dd, const float* wp, float xf, uint4 hv, int s0, int lane, int bx,
    const float* __restrict__ init_param, float* __restrict__ out)
{
    float p0,p1,p2,p3,p4,p5,p6,p7,p8,p9,p10,p11,p12,p13;
    if (dd == 0) {
        p0 = init_param[0];  p1 = init_param[1];  p2 = init_param[2];
        p3 = init_param[3];  p4 = init_param[4];  p5 = init_param[5];
        p6 = init_param[6];  p7 = init_param[7];  p8 = init_param[8];
        p9 = init_param[9];  p10 = init_param[10]; p11 = init_param[11];
        p12 = init_param[12]; p13 = init_param[13];
    } else {
        float h1f[8];
        h1f[0] = __uint_as_float(hv.x << 16);
        h1f[1] = __uint_as_float(hv.x & 0xFFFF0000u);
        h1f[2] = __uint_as_float(hv.y << 16);
        h1f[3] = __uint_as_float(hv.y & 0xFFFF0000u);
        h1f[4] = __uint_as_float(hv.z << 16);
        h1f[5] = __uint_as_float(hv.z & 0xFFFF0000u);
        h1f[6] = __uint_as_float(hv.w << 16);
        h1f[7] = __uint_as_float(hv.w & 0xFFFF0000u);

        // layer 2: f4 accumulators -> v_pk_fma_f32 pairs; ds_read_b128 weights
        f4 h2a = *(const f4*)(wp + 64);
        f4 h2b = *(const f4*)(wp + 68);
        #pragma unroll
        for (int h = 0; h < 8; ++h) {
            f4 wa = *(const f4*)(wp + h * 8);
            f4 wb = *(const f4*)(wp + h * 8 + 4);
            f4 av = splat4(h1f[h]);
            h2a += av * wa;
            h2b += av * wb;
        }
        float h2f[8];
        h2f[0] = tanh_fast(h2a.x); h2f[1] = tanh_fast(h2a.y);
        h2f[2] = tanh_fast(h2a.z); h2f[3] = tanh_fast(h2a.w);
        h2f[4] = tanh_fast(h2b.x); h2f[5] = tanh_fast(h2b.y);
        h2f[6] = tanh_fast(h2b.z); h2f[7] = tanh_fast(h2b.w);

        // layer 3: padded [g][16] rows; pp_d.zw are garbage, discarded
        f4 ppa = *(const f4*)(wp + 200);
        f4 ppb = *(const f4*)(wp + 204);
        f4 ppc = *(const f4*)(wp + 208);
        f4 ppd = *(const f4*)(wp + 212);
        #pragma unroll
        for (int g = 0; g < 8; ++g) {
            const float* wr = wp + 72 + g * 16;
            f4 w0 = *(const f4*)(wr);
            f4 w1 = *(const f4*)(wr + 4);
            f4 w2v = *(const f4*)(wr + 8);
            f4 w3v = *(const f4*)(wr + 12);
            f4 av = splat4(h2f[g]);
            ppa += av * w0;
            ppb += av * w1;
            ppc += av * w2v;
            ppd += av * w3v;
        }
        p0 = ppa.x; p1 = ppa.y; p2 = ppa.z; p3 = ppa.w;
        p4 = ppb.x; p5 = ppb.y; p6 = ppb.z; p7 = ppb.w;
        p8 = ppc.x; p9 = ppc.y; p10 = ppc.z; p11 = ppc.w;
        p12 = ppd.x; p13 = ppd.y;
    }

    // ---- packed RQS spline (w=x-lane, h=y-lane of f2) ----
    f2 e0, e1, e2, e3, e4;
    e0.x = exp_fast(p0); e0.y = exp_fast(p5);
    e1.x = exp_fast(p1); e1.y = exp_fast(p6);
    e2.x = exp_fast(p2); e2.y = exp_fast(p7);
    e3.x = exp_fast(p3); e3.y = exp_fast(p8);
    e4.x = exp_fast(p4); e4.y = exp_fast(p9);
    f2 es = e0 + e1 + e2 + e3 + e4;
    f2 nrm; nrm.x = 0.995f * rcp_fast(es.x); nrm.y = 0.995f * rcp_fast(es.y);

    const f2 minv = {MIN_Wc, MIN_Hc};
    f2 cb0 = splat2(-Bc), acc2 = splat2(0.f);
    acc2 += minv + nrm * e0;  f2 cb1 = splat2(2.f * Bc) * acc2 - splat2(Bc);
    acc2 += minv + nrm * e1;  f2 cb2 = splat2(2.f * Bc) * acc2 - splat2(Bc);
    acc2 += minv + nrm * e2;  f2 cb3 = splat2(2.f * Bc) * acc2 - splat2(Bc);
    acc2 += minv + nrm * e3;  f2 cb4 = splat2(2.f * Bc) * acc2 - splat2(Bc);
    f2 cb5 = splat2(Bc);

    const float xc = fminf(fmaxf(xf, -Bc), Bc);

    // bin select; derivs selected RAW, softplus applied after (2 instead of 4)
    float icw = cb0.x, ich = cb0.y;
    float ibw = cb1.x - cb0.x, ih = cb1.y - cb0.y;
    float rv = p10, rvp = p10;
    bool v_one = true, vp_one = false;
    {
        bool c = xc >= cb1.x; f2 dif = cb2 - cb1;
        icw = c ? cb1.x : icw; ich = c ? cb1.y : ich;
        ibw = c ? dif.x : ibw; ih  = c ? dif.y : ih;
        v_one = c ? false : v_one; rv = c ? p10 : rv; rvp = c ? p11 : rvp;
    }
    {
        bool c = xc >= cb2.x; f2 dif = cb3 - cb2;
        icw = c ? cb2.x : icw; ich = c ? cb2.y : ich;
        ibw = c ? dif.x : ibw; ih  = c ? dif.y : ih;
        rv = c ? p11 : rv; rvp = c ? p12 : rvp;
    }
    {
        bool c = xc >= cb3.x; f2 dif = cb4 - cb3;
        icw = c ? cb3.x : icw; ich = c ? cb3.y : ich;
        ibw = c ? dif.x : ibw; ih  = c ? dif.y : ih;
        rv = c ? p12 : rv; rvp = c ? p13 : rvp;
    }
    {
        bool c = xc >= cb4.x; f2 dif = cb5 - cb4;
        icw = c ? cb4.x : icw; ich = c ? cb4.y : ich;
        ibw = c ? dif.x : ibw; ih  = c ? dif.y : ih;
        rv = c ? p13 : rv; vp_one = c;
    }
    const float idv   = v_one  ? 1.0f : MIN_Dc + softplus_fast(rv);
    const float idvp1 = vp_one ? 1.0f : MIN_Dc + softplus_fast(rvp);

    const float ibw_r = rcp_fast(ibw);
    const float idl = ih * ibw_r;
    const float theta = (xc - icw) * ibw_r;
    const float omt = 1.0f - theta;
    const float tmt = theta * omt;
    const float num = ih * (idl * theta * theta + idv * tmt);
    const float den = idl + (idv + idvp1 - 2.0f * idl) * tmt;
    const float dr = rcp_fast(den);
    const float outv = ich + num * dr;
    const float dnum = idl * idl * (idvp1 * theta * theta + 2.0f * idl * tmt + idv * omt * omt);
    const float ld = log_fast(dnum * dr * dr);   // log(dnum) - 2log(den)

    const bool inside = (xf >= -Bc) && (xf <= Bc);
    const float z = inside ? outv : xf;
    float ldv = inside ? ld : 0.0f;

    out[dd * NN + s0 + lane] = z;   // coalesced

    #pragma unroll
    for (int off = 32; off > 0; off >>= 1) ldv += __shfl_down(ldv, off);
    if (lane == 0) out[NN * DD + dd * (NN / 64) + bx] = ldv;
}

// ---------------- fused kernel -----------------------------------------------
// grid (512, 4): x = 64-sample tile, y = 16-dim group (y==3 idx15 -> dim 0).
// causality: y<2 -> l<32 -> only k<32 contributes (W1 pre-masked) -> 1 MFMA.
#define H1S 136   // u16 row stride: 272B; rows 16B-aligned, 4-bank residue
__global__ __launch_bounds__(256, 5) void fused_kernel(
    const float* __restrict__ x, const float* __restrict__ init_param,
    const ushort* __restrict__ Bp, const float* __restrict__ b1,
    const float* __restrict__ W2, const float* __restrict__ b2,
    const float* __restrict__ W3, const float* __restrict__ b3,
    float* __restrict__ out)
{
    __shared__ ushort h1c[64 * H1S];     // 17408 B
    __shared__ float  wl[16 * WSL];      // 13824 B  -> total 31232 B, 5 blocks/CU
    const int tid = threadIdx.x;
    const int s0 = blockIdx.x * 64;
    const int y  = blockIdx.y;
    const int bx = blockIdx.x;
    const int lane = tid & 63;
    const int wave = __builtin_amdgcn_readfirstlane(tid >> 6);
    const int ln = lane & 15, qg = lane >> 4;
    const int m0 = wave * 16;
    const int l0 = y * 16;

    // spline x values (per-lane gather, latency hidden behind phase 1)
    const float* xrow = x + (size_t)(s0 + lane) * 64;
    const int db = y * 16 + 1 + wave * 4;     // first dim of this wave's group
    float xv0 = xrow[db];
    float xv1 = xrow[db + 1];
    float xv2 = xrow[db + 2];
    float xv3 = xrow[(y == 3 && wave == 3) ? 0 : db + 3];

    // A-fragments (fp32 -> bf16), verified layout: A[m=ln][k=qg*8+j]
    short8 a0, a1;
    {
        const float* xr = x + (size_t)(s0 + m0 + ln) * 64 + qg * 8;
        a0 = pack_a(*(const f4*)xr, *(const f4*)(xr + 4));
        a1 = (y >= 2) ? pack_a(*(const f4*)(xr + 32), *(const f4*)(xr + 36)) : a0;
    }

    // ---- stage this block's 16 dims of W2/b2/W3/b3 into LDS ----
    {   // W2: 16 slots x 64 floats, f4 granularity (256 chunks, 1 iter)
        int s = tid >> 4, o = (tid & 15) * 4;
        if (l0 + s < LL)
            *(f4*)&wl[s * WSL + o] = *(const f4*)&W2[(l0 + s) * 64 + o];
    }
    if (tid < 128) {   // b2: 16 x 8
        int s = tid >> 3, o = tid & 7;
        if (l0 + s < LL) wl[s * WSL + 64 + o] = b2[(l0 + s) * 8 + o];
    }
    // W3: 16 slots x 8 g x 7 f2 (source rows 8B-aligned), padded dest [g][16]
    #pragma unroll
    for (int q0 = 0; q0 < 896; q0 += 256) {
        int q = q0 + tid;
        if (q < 896) {
            int s = q / 56, r = q % 56, g = r / 7, o = r % 7;
            *(f2*)&wl[s * WSL + 72 + g * 16 + o * 2] =
                *(const f2*)&W3[(l0 + s) * 112 + g * 14 + o * 2];
        }
    }
    if (tid < 128) {   // zero W3 pad cols 14,15
        int s = tid >> 3, g = tid & 7;
        *(f2*)&wl[s * WSL + 72 + g * 16 + 14] = splat2(0.f);
    }
    if (tid < 224) {   // b3: 16 x 14
        int s = tid / 14, o = tid % 14;
        wl[s * WSL + 200 + o] = b3[(l0 + s < LL ? l0 + s : 0) * PP + o];
    }
    if (tid < 32) {    // zero b3 pad
        int s = tid >> 1, o = 214 + (tid & 1);
        wl[s * WSL + o] = 0.f;
    }

    // ---- phase 1: MFMA all 128 outcols for this wave's 16 samples ----
    #pragma unroll
    for (int nt = 0; nt < 8; ++nt) {
        int ncol = y * 128 + nt * 16 + ln;
        const short8* bp8 = (const short8*)(Bp + ncol * 64 + qg * 8);
        f32x4 acc = {0.f, 0.f, 0.f, 0.f};
        acc = __builtin_amdgcn_mfma_f32_16x16x32_bf16(a0, bp8[0], acc, 0, 0, 0);
        if (y >= 2)
            acc = __builtin_amdgcn_mfma_f32_16x16x32_bf16(a1, bp8[4], acc, 0, 0, 0);
        float bias = (ncol < 504) ? b1[ncol] : 0.f;
        #pragma unroll
        for (int r = 0; r < 4; ++r) {
            float v = tanh_fast(acc[r] + bias);
            h1c[(m0 + qg * 4 + r) * H1S + nt * 16 + ln] = to_bf16u(v);
        }
    }
    __syncthreads();   // the only barrier (covers weight staging + h1c)

    // h1 fragments for this wave's 4 dims — 4 static b128 reads
    const uint4* hp = (const uint4*)&h1c[lane * H1S + wave * 32];
    uint4 hv0 = hp[0], hv1 = hp[1], hv2 = hp[2], hv3 = hp[3];

    // ---- phase 2: 4 dims, explicit calls (static everything) ----
    const int sl = wave * 4;
    do_dim(db,     wl + (sl)     * WSL, xv0, hv0, s0, lane, bx, init_param, out);
    do_dim(db + 1, wl + (sl + 1) * WSL, xv1, hv1, s0, lane, bx, init_param, out);
    do_dim(db + 2, wl + (sl + 2) * WSL, xv2, hv2, s0, lane, bx, init_param, out);
    do_dim((y == 3 && wave == 3) ? 0 : db + 3,
                   wl + (sl + 3) * WSL, xv3, hv3, s0, lane, bx, init_param, out);
}

extern "C" void kernel_launch(void* const* d_in, const int* in_sizes, int n_in,
                              void* d_out, int out_size, void* d_ws, size_t ws_size,
                              hipStream_t stream) {
    const float* x          = (const float*)d_in[0];
    const float* init_param = (const float*)d_in[1];
    const float* W1         = (const float*)d_in[2];
    const float* b1         = (const float*)d_in[3];
    const float* W2         = (const float*)d_in[4];
    const float* b2         = (const float*)d_in[5];
    const float* W3         = (const float*)d_in[6];
    const float* b3         = (const float*)d_in[7];
    float* out = (float*)d_out;

    ushort* Bp = (ushort*)d_ws;            // 512*64 bf16 = 64 KB

    pack_b1<<<128, 256, 0, stream>>>(W1, Bp);
    fused_kernel<<<dim3(512, 4), 256, 0, stream>>>(x, init_param, Bp, b1,
                                                   W2, b2, W3, b3, out);
}